// Round 6
// baseline (262.183 us; speedup 1.0000x reference)
//
#include <hip/hip_runtime.h>
#include <math.h>

#define HWSZ 6400
#define WIMG 80
#define HIMG 80
#define BEPS 1e-5f

typedef __attribute__((ext_vector_type(8))) short short8;
typedef __attribute__((ext_vector_type(4))) short s16x4;
typedef __attribute__((ext_vector_type(4))) float f32x4;
typedef __attribute__((ext_vector_type(4))) int i32x4;

__device__ __forceinline__ unsigned short f2b(float f) {
    unsigned u = __builtin_bit_cast(unsigned, f);
    u += 0x7fffu + ((u >> 16) & 1u);
    return (unsigned short)(u >> 16);
}
// round-to-nearest-even-ish pack of two f32 -> bf16x2 via v_perm
__device__ __forceinline__ int f2b_pk(float flo, float fhi) {
    unsigned lo = __builtin_bit_cast(unsigned, flo);
    unsigned hi = __builtin_bit_cast(unsigned, fhi);
    lo += 0x7fffu + ((lo >> 16) & 1u);
    hi += 0x7fffu + ((hi >> 16) & 1u);
    return (int)__builtin_amdgcn_perm(hi, lo, 0x07060302u);
}
__device__ __forceinline__ float b2f(unsigned short h) {
    unsigned u = ((unsigned)h) << 16;
    return __builtin_bit_cast(float, u);
}
__device__ __forceinline__ float silu_f(float t) { return t / (1.f + __expf(-t)); }

// B-fragment LDS layout: [kstep(sub)][ntile][n16][q-octet][8], row stride 40
// shorts (80 B): quarter-wave read pattern is the minimal 2-way bank alias.
#define BPOS(sub, nt, n16, q) (((((sub)*4 + (nt))*16 + (n16))*40) + (q)*8)

// ---------------- prep: BN-fold + bf16 A-fragment prepack -------------------
// apk*: [mt][ks][lane][8] bf16, element = w'[o = mt*16+(lane&15)][k = ks*32+(lane>>4)*8+j]
// conv kernels use k' = tap*128 + c ordering.
__global__ __launch_bounds__(256) void k_prep(
    const float* __restrict__ cv1w, const float* __restrict__ g1, const float* __restrict__ b1,
    const float* __restrict__ m1, const float* __restrict__ v1,
    const float* __restrict__ offw, const float* __restrict__ offb,
    const float* __restrict__ dcnw, const float* __restrict__ dcnb,
    const float* __restrict__ g2, const float* __restrict__ b2,
    const float* __restrict__ m2, const float* __restrict__ v2,
    const float* __restrict__ cv2w, const float* __restrict__ g3, const float* __restrict__ b3,
    const float* __restrict__ m3, const float* __restrict__ v3,
    unsigned short* __restrict__ apk1, unsigned short* __restrict__ apko,
    unsigned short* __restrict__ apkd, unsigned short* __restrict__ apk2,
    float* __restrict__ bias1, float* __restrict__ biaso,
    float* __restrict__ bias2, float* __restrict__ bias3)
{
    int idx = blockIdx.x * 256 + threadIdx.x;
    if (idx < 32768) {                       // cv1: [8 mt][8 ks][64][8], K = 256 ch
        int j = idx & 7, L = (idx >> 3) & 63, ks = (idx >> 9) & 7, mt = idx >> 12;
        int o = mt * 16 + (L & 15), k = ks * 32 + (L >> 4) * 8 + j;
        float inv = g1[o] * rsqrtf(v1[o] + BEPS);
        apk1[idx] = f2b(cv1w[o * 256 + k] * inv);
    } else if (idx < 69632) {                // off: [2 mt][36 ks][64][8], k' = n*128+c, rows>=27 zero
        int t = idx - 32768;
        int j = t & 7, L = (t >> 3) & 63;
        int mt = t / 18432, rem = t % 18432, ks = rem >> 9;
        int o = mt * 16 + (L & 15);
        int kp = ks * 32 + (L >> 4) * 8 + j;
        int n = kp >> 7, c = kp & 127;
        float wv = (o < 27) ? offw[(size_t)(o * 128 + c) * 9 + n] : 0.f;
        apko[t] = f2b(wv);
    } else if (idx < 217088) {               // dcn: [8 mt][36 ks][64][8], k' = n*128+c, BN2 fold
        int t = idx - 69632;
        int j = t & 7, L = (t >> 3) & 63;
        int mt = t / 18432, rem = t % 18432, ks = rem >> 9;
        int o = mt * 16 + (L & 15);
        int kp = ks * 32 + (L >> 4) * 8 + j;
        int n = kp >> 7, c = kp & 127;
        float inv = g2[o] * rsqrtf(v2[o] + BEPS);
        apkd[t] = f2b(dcnw[(size_t)(o * 128 + c) * 9 + n] * inv);
    } else if (idx < 249856) {               // cv2: [16 mt][4 ks][64][8], BN3 fold
        int t = idx - 217088;
        int j = t & 7, L = (t >> 3) & 63, ks = (t >> 9) & 3, mt = t >> 11;
        int o = mt * 16 + (L & 15), k = ks * 32 + (L >> 4) * 8 + j;
        float inv = g3[o] * rsqrtf(v3[o] + BEPS);
        apk2[t] = f2b(cv2w[o * 128 + k] * inv);
    } else if (idx < 250395) {               // biases
        int t = idx - 249856;
        if (t < 128) { float inv = g1[t] * rsqrtf(v1[t] + BEPS); bias1[t] = b1[t] - m1[t] * inv; }
        else if (t < 155) { biaso[t - 128] = offb[t - 128]; }
        else if (t < 283) { int o = t - 155; float inv = g2[o] * rsqrtf(v2[o] + BEPS);
                            bias2[o] = dcnb[o] * inv + b2[o] - m2[o] * inv; }
        else { int o = t - 283; float inv = g3[o] * rsqrtf(v3[o] + BEPS); bias3[o] = b3[o] - m3[o] * inv; }
    }
}

// ---------------- cv1: 1x1 (256->128) + bn1 + silu -> y1t (pixel-major bf16) ----
// grid 800, 256 thr. Register-direct B-frags; full unroll for load MLP.
__global__ __launch_bounds__(256) void k_cv1(
    const float* __restrict__ x, const unsigned short* __restrict__ apk1,
    const float* __restrict__ bias1, unsigned short* __restrict__ y1t)
{
    int blk = blockIdx.x;
    int b = blk & 7, pt = blk >> 3;        // XCD swizzle: image b -> XCD b
    int p0 = pt * 64;
    int tid = threadIdx.x;
    int lane = tid & 63, w = tid >> 6;
    int n16 = lane & 15, qd = lane >> 4;
    int px = p0 + w * 16 + n16;
    const float* xb = x + (size_t)b * 256 * HWSZ + px;
    f32x4 acc[8];
#pragma unroll
    for (int mt = 0; mt < 8; ++mt) acc[mt] = (f32x4){0.f, 0.f, 0.f, 0.f};
#pragma unroll
    for (int ks = 0; ks < 8; ++ks) {
        float xv[8];
#pragma unroll
        for (int j = 0; j < 8; ++j)
            xv[j] = xb[(size_t)(ks * 32 + qd * 8 + j) * HWSZ];
        i32x4 bi;
#pragma unroll
        for (int t = 0; t < 4; ++t) bi[t] = f2b_pk(xv[2 * t], xv[2 * t + 1]);
        short8 bf = __builtin_bit_cast(short8, bi);
#pragma unroll
        for (int mt = 0; mt < 8; ++mt) {
            short8 af = *(const short8*)&apk1[(size_t)((mt * 8 + ks) * 64 + lane) * 8];
            acc[mt] = __builtin_amdgcn_mfma_f32_16x16x32_bf16(af, bf, acc[mt], 0, 0, 0);
        }
    }
    unsigned short* ytb = y1t + ((size_t)b * HWSZ + px) * 128;
#pragma unroll
    for (int mt = 0; mt < 8; ++mt) {
        int o0 = mt * 16 + qd * 4;
        s16x4 v;
#pragma unroll
        for (int r = 0; r < 4; ++r)
            v[r] = (short)f2b(silu_f(acc[mt][r] + bias1[o0 + r]));
        *(s16x4*)&ytb[o0] = v;
    }
}

// ---------------- off: 3x3 conv (128->27) + bias, sigmoid on mask ------------
// grid 800, 256 thr. Register-direct: lane = (pixel n16, ch-octet qd); no LDS,
// no barriers; 36 independent gathers pipeline against the MFMAs.
__global__ __launch_bounds__(256) void k_off(
    const unsigned short* __restrict__ y1t, const unsigned short* __restrict__ apko,
    const float* __restrict__ biaso, float* __restrict__ raw)
{
    int blk = blockIdx.x;
    int b = blk & 7, pt = blk >> 3;        // XCD swizzle
    int p0 = pt * 64;
    int tid = threadIdx.x;
    int lane = tid & 63, w = tid >> 6;
    int n16 = lane & 15, qd = lane >> 4;
    int pxl = w * 16 + n16;
    int p = p0 + pxl;
    int h = p / WIMG, wx = p % WIMG;
    const unsigned short* yb = y1t + (size_t)b * HWSZ * 128 + qd * 8;
    f32x4 acc[2];
    acc[0] = (f32x4){0.f, 0.f, 0.f, 0.f};
    acc[1] = (f32x4){0.f, 0.f, 0.f, 0.f};
    const short8 zz = {0, 0, 0, 0, 0, 0, 0, 0};
#pragma unroll
    for (int n = 0; n < 9; ++n) {
        int hh = h - 1 + n / 3, ww = wx - 1 + n % 3;
        bool valid = ((unsigned)hh < HIMG) && ((unsigned)ww < WIMG);
        int spx = valid ? hh * WIMG + ww : 0;
        const unsigned short* ys = yb + (size_t)spx * 128;
        short8 v[4];
#pragma unroll
        for (int sub = 0; sub < 4; ++sub) {
            v[sub] = *(const short8*)&ys[sub * 32];
            if (!valid) v[sub] = zz;
        }
#pragma unroll
        for (int sub = 0; sub < 4; ++sub) {
            int ks = n * 4 + sub;
            short8 af0 = *(const short8*)&apko[(size_t)(ks * 64 + lane) * 8];
            short8 af1 = *(const short8*)&apko[(size_t)((36 + ks) * 64 + lane) * 8];
            acc[0] = __builtin_amdgcn_mfma_f32_16x16x32_bf16(af0, v[sub], acc[0], 0, 0, 0);
            acc[1] = __builtin_amdgcn_mfma_f32_16x16x32_bf16(af1, v[sub], acc[1], 0, 0, 0);
        }
    }
    float* rb = raw + (size_t)b * 27 * HWSZ + p0 + w * 16 + n16;
#pragma unroll
    for (int mi = 0; mi < 2; ++mi)
#pragma unroll
        for (int r = 0; r < 4; ++r) {
            int o = mi * 16 + qd * 4 + r;
            if (o < 27) {
                float t = acc[mi][r] + biaso[o];
                if (o >= 18) t = 1.f / (1.f + __expf(-t));
                rb[(size_t)o * HWSZ] = t;
            }
        }
}

// ---------------- dcn: DCNv2 + bn2 + silu -> zt (pixel-major bf16) -----------
// grid 800, 256 thr. R5 cooperative structure + perm-based bf16 pair packing.
__global__ __launch_bounds__(256) void k_dcn(
    const unsigned short* __restrict__ y1t, const float* __restrict__ raw,
    const unsigned short* __restrict__ apkd, const float* __restrict__ bias2,
    unsigned short* __restrict__ zt)
{
    __shared__ float swgt[4][9][64];
    __shared__ unsigned short sidx[4][9][64];
    __shared__ __align__(16) unsigned short sV[10240];
    int blk = blockIdx.x;
    int b = blk & 7, pt = blk >> 3;        // XCD swizzle
    int p0 = pt * 64;
    int tid = threadIdx.x;

    // stage 1: decode offsets -> 4 corner (idx, weight) per (tap, pixel)
    for (int i = tid; i < 576; i += 256) {
        int n = i / 64, pp = i % 64;
        int p = p0 + pp;
        int h = p / WIMG, wx = p % WIMG;
        const float* rb = raw + (size_t)b * 27 * HWSZ + p;
        float dy = rb[(size_t)(2 * n) * HWSZ];
        float dx = rb[(size_t)(2 * n + 1) * HWSZ];
        float mk = rb[(size_t)(18 + n) * HWSZ];
        float py = (float)(h - 1 + n / 3) + dy;
        float px = (float)(wx - 1 + n % 3) + dx;
        float y0f = floorf(py), x0f = floorf(px);
        float fy = py - y0f, fx = px - x0f;
        int y0 = (int)y0f, x0 = (int)x0f;
#pragma unroll
        for (int k = 0; k < 4; ++k) {
            int yy = y0 + (k >> 1);
            int xx = x0 + (k & 1);
            bool valid = ((unsigned)yy < HIMG) && ((unsigned)xx < WIMG);
            float wk = ((k >> 1) ? fy : 1.f - fy) * ((k & 1) ? fx : 1.f - fx);
            wk = valid ? wk * mk : 0.f;
            int yc = min(max(yy, 0), HIMG - 1);
            int xc = min(max(xx, 0), WIMG - 1);
            sidx[k][n][pp] = (unsigned short)(yc * WIMG + xc);
            swgt[k][n][pp] = wk;
        }
    }
    __syncthreads();

    int lane = tid & 63, w = tid >> 6;
    int n16 = lane & 15, qd = lane >> 4;
    int pxl = tid >> 2, q = tid & 3;
    const unsigned short* yb = y1t + (size_t)b * HWSZ * 128;
    f32x4 acc[2][4];
#pragma unroll
    for (int mi = 0; mi < 2; ++mi)
#pragma unroll
        for (int nt = 0; nt < 4; ++nt) acc[mi][nt] = (f32x4){0.f, 0.f, 0.f, 0.f};

    for (int n = 0; n < 9; ++n) {
        // gather + bilinear: this thread = (pixel pxl, ch-octet q), 32 ch across 4 ksteps
        float av[4][8];
#pragma unroll
        for (int sub = 0; sub < 4; ++sub)
#pragma unroll
            for (int j = 0; j < 8; ++j) av[sub][j] = 0.f;
#pragma unroll
        for (int k = 0; k < 4; ++k) {
            float wk = swgt[k][n][pxl];
            const unsigned short* ys = yb + (size_t)sidx[k][n][pxl] * 128 + q * 8;
#pragma unroll
            for (int sub = 0; sub < 4; ++sub) {
                short8 v = *(const short8*)&ys[sub * 32];
#pragma unroll
                for (int j = 0; j < 8; ++j)
                    av[sub][j] = fmaf(wk, b2f((unsigned short)v[j]), av[sub][j]);
            }
        }
#pragma unroll
        for (int sub = 0; sub < 4; ++sub) {
            i32x4 bi;
#pragma unroll
            for (int t = 0; t < 4; ++t)
                bi[t] = f2b_pk(av[sub][2 * t], av[sub][2 * t + 1]);
            *(i32x4*)&sV[BPOS(sub, pxl >> 4, pxl & 15, q)] = bi;
        }
        __syncthreads();
#pragma unroll
        for (int sub = 0; sub < 4; ++sub) {
            int ks = n * 4 + sub;
            short8 bf[4];
#pragma unroll
            for (int nt = 0; nt < 4; ++nt)
                bf[nt] = *(const short8*)&sV[BPOS(sub, nt, n16, qd)];
#pragma unroll
            for (int mi = 0; mi < 2; ++mi) {
                short8 af = *(const short8*)&apkd[(size_t)(((2 * w + mi) * 36 + ks) * 64 + lane) * 8];
#pragma unroll
                for (int nt = 0; nt < 4; ++nt)
                    acc[mi][nt] = __builtin_amdgcn_mfma_f32_16x16x32_bf16(af, bf[nt], acc[mi][nt], 0, 0, 0);
            }
        }
        __syncthreads();
    }
    // epilogue: bn2(fused)+silu -> pixel-major bf16, direct 8B stores
    unsigned short* zb = zt + ((size_t)b * HWSZ + p0) * 128;
#pragma unroll
    for (int mi = 0; mi < 2; ++mi)
#pragma unroll
        for (int nt = 0; nt < 4; ++nt) {
            int o0 = (2 * w + mi) * 16 + qd * 4;
            int px = nt * 16 + n16;
            s16x4 v;
#pragma unroll
            for (int r = 0; r < 4; ++r)
                v[r] = (short)f2b(silu_f(acc[mi][nt][r] + bias2[o0 + r]));
            *(s16x4*)&zb[(size_t)px * 128 + o0] = v;
        }
}

// ---------------- cv2: 1x1 (128->256) + bn3 + silu + residual ----------------
// grid 800, 256 thr. Transposed MFMA (A = z-pixels, B = weights): D gives each
// lane 4 consecutive pixels of one o -> float4 residual loads + float4 stores.
__global__ __launch_bounds__(256) void k_cv2(
    const unsigned short* __restrict__ zt, const float* __restrict__ x,
    const unsigned short* __restrict__ apk2, const float* __restrict__ bias3,
    float* __restrict__ out)
{
    int blk = blockIdx.x;
    int b = blk & 7, pt = blk >> 3;        // XCD swizzle
    int p0 = pt * 64;
    int tid = threadIdx.x;
    int lane = tid & 63, w = tid >> 6;
    int n16 = lane & 15, qd = lane >> 4;
    const unsigned short* zb = zt + ((size_t)b * HWSZ + p0) * 128;
    f32x4 acc[4][4];   // [mt = pixel-tile][ntl = local o-tile]
#pragma unroll
    for (int mt = 0; mt < 4; ++mt)
#pragma unroll
        for (int ntl = 0; ntl < 4; ++ntl) acc[mt][ntl] = (f32x4){0.f, 0.f, 0.f, 0.f};
#pragma unroll
    for (int ks = 0; ks < 4; ++ks) {
        short8 az[4];
#pragma unroll
        for (int mt = 0; mt < 4; ++mt)
            az[mt] = *(const short8*)&zb[(size_t)(mt * 16 + n16) * 128 + ks * 32 + qd * 8];
#pragma unroll
        for (int ntl = 0; ntl < 4; ++ntl) {
            int nt = w * 4 + ntl;
            short8 bw = *(const short8*)&apk2[(size_t)((nt * 4 + ks) * 64 + lane) * 8];
#pragma unroll
            for (int mt = 0; mt < 4; ++mt)
                acc[mt][ntl] = __builtin_amdgcn_mfma_f32_16x16x32_bf16(az[mt], bw, acc[mt][ntl], 0, 0, 0);
        }
    }
    const float* xb = x + (size_t)b * 256 * HWSZ;
    float* ob = out + (size_t)b * 256 * HWSZ;
#pragma unroll
    for (int mt = 0; mt < 4; ++mt) {
        int px = p0 + mt * 16 + qd * 4;
#pragma unroll
        for (int ntl = 0; ntl < 4; ++ntl) {
            int o = (w * 4 + ntl) * 16 + n16;
            float bv = bias3[o];
            size_t base = (size_t)o * HWSZ + px;
            float4 xv = *(const float4*)&xb[base];
            float4 r;
            r.x = xv.x + silu_f(acc[mt][ntl][0] + bv);
            r.y = xv.y + silu_f(acc[mt][ntl][1] + bv);
            r.z = xv.z + silu_f(acc[mt][ntl][2] + bv);
            r.w = xv.w + silu_f(acc[mt][ntl][3] + bv);
            *(float4*)&ob[base] = r;
        }
    }
}

extern "C" void kernel_launch(void* const* d_in, const int* in_sizes, int n_in,
                              void* d_out, int out_size, void* d_ws, size_t ws_size,
                              hipStream_t stream) {
    const float* x     = (const float*)d_in[0];
    const float* cv1w  = (const float*)d_in[1];
    const float* bn1g  = (const float*)d_in[2];
    const float* bn1b  = (const float*)d_in[3];
    const float* bn1m  = (const float*)d_in[4];
    const float* bn1v  = (const float*)d_in[5];
    const float* offw  = (const float*)d_in[6];
    const float* offb  = (const float*)d_in[7];
    const float* dcnw  = (const float*)d_in[8];
    const float* dcnb  = (const float*)d_in[9];
    const float* bn2g  = (const float*)d_in[10];
    const float* bn2b  = (const float*)d_in[11];
    const float* bn2m  = (const float*)d_in[12];
    const float* bn2v  = (const float*)d_in[13];
    const float* cv2w  = (const float*)d_in[14];
    const float* bn3g  = (const float*)d_in[15];
    const float* bn3b  = (const float*)d_in[16];
    const float* bn3m  = (const float*)d_in[17];
    const float* bn3v  = (const float*)d_in[18];
    float* out = (float*)d_out;

    // workspace layout (float units)
    float* base = (float*)d_ws;
    unsigned short* y1t = (unsigned short*)base;                 // 8*6400*128 bf16 = 3,276,800 f
    float* raw   = base + 3276800;                               // 8*27*6400   = 1,382,400 f
    unsigned short* zt  = (unsigned short*)(base + 4659200);     // 8*6400*128 bf16 = 3,276,800 f
    unsigned short* apk1 = (unsigned short*)(base + 7936000);    // 32768  ush = 16384 f
    unsigned short* apko = (unsigned short*)(base + 7952384);    // 36864  ush = 18432 f
    unsigned short* apkd = (unsigned short*)(base + 7970816);    // 147456 ush = 73728 f
    unsigned short* apk2 = (unsigned short*)(base + 8044544);    // 32768  ush = 16384 f
    float* bias1 = base + 8060928;                               // 128
    float* biaso = base + 8061056;                               // 27 (pad 32)
    float* bias2 = base + 8061088;                               // 128
    float* bias3 = base + 8061216;                               // 256

    k_prep<<<979, 256, 0, stream>>>(cv1w, bn1g, bn1b, bn1m, bn1v,
                                    offw, offb, dcnw, dcnb,
                                    bn2g, bn2b, bn2m, bn2v,
                                    cv2w, bn3g, bn3b, bn3m, bn3v,
                                    apk1, apko, apkd, apk2,
                                    bias1, biaso, bias2, bias3);
    k_cv1<<<800, 256, 0, stream>>>(x, apk1, bias1, y1t);
    k_off<<<800, 256, 0, stream>>>(y1t, apko, biaso, raw);
    k_dcn<<<800, 256, 0, stream>>>(y1t, raw, apkd, bias2, zt);
    k_cv2<<<800, 256, 0, stream>>>(zt, x, apk2, bias3, out);
}

// Round 7
// 239.111 us; speedup vs baseline: 1.0965x; 1.0965x over previous
//
#include <hip/hip_runtime.h>
#include <math.h>

#define HWSZ 6400
#define WIMG 80
#define HIMG 80
#define BEPS 1e-5f

typedef __attribute__((ext_vector_type(8))) short short8;
typedef __attribute__((ext_vector_type(4))) short s16x4;
typedef __attribute__((ext_vector_type(4))) float f32x4;
typedef __attribute__((ext_vector_type(4))) int i32x4;

__device__ __forceinline__ unsigned short f2b(float f) {
    unsigned u = __builtin_bit_cast(unsigned, f);
    u += 0x7fffu + ((u >> 16) & 1u);
    return (unsigned short)(u >> 16);
}
// pack two f32 -> bf16x2 via v_perm (used only in cv1, where R6 showed no regression)
__device__ __forceinline__ int f2b_pk(float flo, float fhi) {
    unsigned lo = __builtin_bit_cast(unsigned, flo);
    unsigned hi = __builtin_bit_cast(unsigned, fhi);
    lo += 0x7fffu + ((lo >> 16) & 1u);
    hi += 0x7fffu + ((hi >> 16) & 1u);
    return (int)__builtin_amdgcn_perm(hi, lo, 0x07060302u);
}
__device__ __forceinline__ float b2f(unsigned short h) {
    unsigned u = ((unsigned)h) << 16;
    return __builtin_bit_cast(float, u);
}
__device__ __forceinline__ float silu_f(float t) { return t / (1.f + __expf(-t)); }

// P=64 B-frag LDS layout (k_off legacy): row stride 40 shorts
#define BPOS(sub, nt, n16, q) (((((sub)*4 + (nt))*16 + (n16))*40) + (q)*8)
// P=32 B-frag LDS layout (k_dcn): [sub 0..3][nt 0..1][n16][oct 0..3][8], stride 40
#define BPOS32(sub, nt, n16, oct) (((((sub)*2 + (nt))*16 + (n16))*40) + (oct)*8)

// ---------------- prep: BN-fold + bf16 A-fragment prepack -------------------
__global__ __launch_bounds__(256) void k_prep(
    const float* __restrict__ cv1w, const float* __restrict__ g1, const float* __restrict__ b1,
    const float* __restrict__ m1, const float* __restrict__ v1,
    const float* __restrict__ offw, const float* __restrict__ offb,
    const float* __restrict__ dcnw, const float* __restrict__ dcnb,
    const float* __restrict__ g2, const float* __restrict__ b2,
    const float* __restrict__ m2, const float* __restrict__ v2,
    const float* __restrict__ cv2w, const float* __restrict__ g3, const float* __restrict__ b3,
    const float* __restrict__ m3, const float* __restrict__ v3,
    unsigned short* __restrict__ apk1, unsigned short* __restrict__ apko,
    unsigned short* __restrict__ apkd, unsigned short* __restrict__ apk2,
    float* __restrict__ bias1, float* __restrict__ biaso,
    float* __restrict__ bias2, float* __restrict__ bias3)
{
    int idx = blockIdx.x * 256 + threadIdx.x;
    if (idx < 32768) {                       // cv1: [8 mt][8 ks][64][8], K = 256 ch
        int j = idx & 7, L = (idx >> 3) & 63, ks = (idx >> 9) & 7, mt = idx >> 12;
        int o = mt * 16 + (L & 15), k = ks * 32 + (L >> 4) * 8 + j;
        float inv = g1[o] * rsqrtf(v1[o] + BEPS);
        apk1[idx] = f2b(cv1w[o * 256 + k] * inv);
    } else if (idx < 69632) {                // off: [2 mt][36 ks][64][8], k' = n*128+c
        int t = idx - 32768;
        int j = t & 7, L = (t >> 3) & 63;
        int mt = t / 18432, rem = t % 18432, ks = rem >> 9;
        int o = mt * 16 + (L & 15);
        int kp = ks * 32 + (L >> 4) * 8 + j;
        int n = kp >> 7, c = kp & 127;
        float wv = (o < 27) ? offw[(size_t)(o * 128 + c) * 9 + n] : 0.f;
        apko[t] = f2b(wv);
    } else if (idx < 217088) {               // dcn: [8 mt][36 ks][64][8], k' = n*128+c, BN2 fold
        int t = idx - 69632;
        int j = t & 7, L = (t >> 3) & 63;
        int mt = t / 18432, rem = t % 18432, ks = rem >> 9;
        int o = mt * 16 + (L & 15);
        int kp = ks * 32 + (L >> 4) * 8 + j;
        int n = kp >> 7, c = kp & 127;
        float inv = g2[o] * rsqrtf(v2[o] + BEPS);
        apkd[t] = f2b(dcnw[(size_t)(o * 128 + c) * 9 + n] * inv);
    } else if (idx < 249856) {               // cv2: [16 mt][4 ks][64][8], BN3 fold
        int t = idx - 217088;
        int j = t & 7, L = (t >> 3) & 63, ks = (t >> 9) & 3, mt = t >> 11;
        int o = mt * 16 + (L & 15), k = ks * 32 + (L >> 4) * 8 + j;
        float inv = g3[o] * rsqrtf(v3[o] + BEPS);
        apk2[t] = f2b(cv2w[o * 128 + k] * inv);
    } else if (idx < 250395) {               // biases
        int t = idx - 249856;
        if (t < 128) { float inv = g1[t] * rsqrtf(v1[t] + BEPS); bias1[t] = b1[t] - m1[t] * inv; }
        else if (t < 155) { biaso[t - 128] = offb[t - 128]; }
        else if (t < 283) { int o = t - 155; float inv = g2[o] * rsqrtf(v2[o] + BEPS);
                            bias2[o] = dcnb[o] * inv + b2[o] - m2[o] * inv; }
        else { int o = t - 283; float inv = g3[o] * rsqrtf(v3[o] + BEPS); bias3[o] = b3[o] - m3[o] * inv; }
    }
}

// ---------------- cv1: 1x1 (256->128) + bn1 + silu -> y1t (pixel-major bf16) ----
// grid 800, 256 thr. Register-direct B-frags (R6 verified).
__global__ __launch_bounds__(256) void k_cv1(
    const float* __restrict__ x, const unsigned short* __restrict__ apk1,
    const float* __restrict__ bias1, unsigned short* __restrict__ y1t)
{
    int blk = blockIdx.x;
    int b = blk & 7, pt = blk >> 3;        // XCD swizzle: image b -> XCD b
    int p0 = pt * 64;
    int tid = threadIdx.x;
    int lane = tid & 63, w = tid >> 6;
    int n16 = lane & 15, qd = lane >> 4;
    int px = p0 + w * 16 + n16;
    const float* xb = x + (size_t)b * 256 * HWSZ + px;
    f32x4 acc[8];
#pragma unroll
    for (int mt = 0; mt < 8; ++mt) acc[mt] = (f32x4){0.f, 0.f, 0.f, 0.f};
#pragma unroll
    for (int ks = 0; ks < 8; ++ks) {
        float xv[8];
#pragma unroll
        for (int j = 0; j < 8; ++j)
            xv[j] = xb[(size_t)(ks * 32 + qd * 8 + j) * HWSZ];
        i32x4 bi;
#pragma unroll
        for (int t = 0; t < 4; ++t) bi[t] = f2b_pk(xv[2 * t], xv[2 * t + 1]);
        short8 bf = __builtin_bit_cast(short8, bi);
#pragma unroll
        for (int mt = 0; mt < 8; ++mt) {
            short8 af = *(const short8*)&apk1[(size_t)((mt * 8 + ks) * 64 + lane) * 8];
            acc[mt] = __builtin_amdgcn_mfma_f32_16x16x32_bf16(af, bf, acc[mt], 0, 0, 0);
        }
    }
    unsigned short* ytb = y1t + ((size_t)b * HWSZ + px) * 128;
#pragma unroll
    for (int mt = 0; mt < 8; ++mt) {
        int o0 = mt * 16 + qd * 4;
        s16x4 v;
#pragma unroll
        for (int r = 0; r < 4; ++r)
            v[r] = (short)f2b(silu_f(acc[mt][r] + bias1[o0 + r]));
        *(s16x4*)&ytb[o0] = v;
    }
}

// ---------------- off: 3x3 conv (128->27) + bias, sigmoid on mask ------------
// grid 800, 256 thr. Register-direct (R6 verified).
__global__ __launch_bounds__(256) void k_off(
    const unsigned short* __restrict__ y1t, const unsigned short* __restrict__ apko,
    const float* __restrict__ biaso, float* __restrict__ raw)
{
    int blk = blockIdx.x;
    int b = blk & 7, pt = blk >> 3;        // XCD swizzle
    int p0 = pt * 64;
    int tid = threadIdx.x;
    int lane = tid & 63, w = tid >> 6;
    int n16 = lane & 15, qd = lane >> 4;
    int pxl = w * 16 + n16;
    int p = p0 + pxl;
    int h = p / WIMG, wx = p % WIMG;
    const unsigned short* yb = y1t + (size_t)b * HWSZ * 128 + qd * 8;
    f32x4 acc[2];
    acc[0] = (f32x4){0.f, 0.f, 0.f, 0.f};
    acc[1] = (f32x4){0.f, 0.f, 0.f, 0.f};
    const short8 zz = {0, 0, 0, 0, 0, 0, 0, 0};
#pragma unroll
    for (int n = 0; n < 9; ++n) {
        int hh = h - 1 + n / 3, ww = wx - 1 + n % 3;
        bool valid = ((unsigned)hh < HIMG) && ((unsigned)ww < WIMG);
        int spx = valid ? hh * WIMG + ww : 0;
        const unsigned short* ys = yb + (size_t)spx * 128;
        short8 v[4];
#pragma unroll
        for (int sub = 0; sub < 4; ++sub) {
            v[sub] = *(const short8*)&ys[sub * 32];
            if (!valid) v[sub] = zz;
        }
#pragma unroll
        for (int sub = 0; sub < 4; ++sub) {
            int ks = n * 4 + sub;
            short8 af0 = *(const short8*)&apko[(size_t)(ks * 64 + lane) * 8];
            short8 af1 = *(const short8*)&apko[(size_t)((36 + ks) * 64 + lane) * 8];
            acc[0] = __builtin_amdgcn_mfma_f32_16x16x32_bf16(af0, v[sub], acc[0], 0, 0, 0);
            acc[1] = __builtin_amdgcn_mfma_f32_16x16x32_bf16(af1, v[sub], acc[1], 0, 0, 0);
        }
    }
    float* rb = raw + (size_t)b * 27 * HWSZ + p0 + w * 16 + n16;
#pragma unroll
    for (int mi = 0; mi < 2; ++mi)
#pragma unroll
        for (int r = 0; r < 4; ++r) {
            int o = mi * 16 + qd * 4 + r;
            if (o < 27) {
                float t = acc[mi][r] + biaso[o];
                if (o >= 18) t = 1.f / (1.f + __expf(-t));
                rb[(size_t)o * HWSZ] = t;
            }
        }
}

// ---------------- dcn: DCNv2 + bn2 + silu -> zt (pixel-major bf16) -----------
// grid 1600, 256 thr. P=32 pixel tile for occupancy (39%->78% wave-supply cap).
// Cooperative gather: thread = (pixel pxl 0..31, ch-16-pair q8 0..7).
// MFMA: M=128 (8 mt), N=32 (2 nt); wave w owns mt {2w,2w+1}, acc 16 VGPR.
__global__ __launch_bounds__(256) void k_dcn(
    const unsigned short* __restrict__ y1t, const float* __restrict__ raw,
    const unsigned short* __restrict__ apkd, const float* __restrict__ bias2,
    unsigned short* __restrict__ zt)
{
    __shared__ float swgt[4][9][32];
    __shared__ unsigned short sidx[4][9][32];
    __shared__ __align__(16) unsigned short sV[5120];   // 4 sub * 2 nt * 16 * 40
    int blk = blockIdx.x;
    int b = blk & 7, pt = blk >> 3;        // XCD swizzle, pt 0..199
    int p0 = pt * 32;
    int tid = threadIdx.x;

    // stage 1: decode offsets -> 4 corner (idx, weight) per (tap, pixel)
    for (int i = tid; i < 288; i += 256) {
        int n = i >> 5, pp = i & 31;
        int p = p0 + pp;
        int h = p / WIMG, wx = p % WIMG;
        const float* rb = raw + (size_t)b * 27 * HWSZ + p;
        float dy = rb[(size_t)(2 * n) * HWSZ];
        float dx = rb[(size_t)(2 * n + 1) * HWSZ];
        float mk = rb[(size_t)(18 + n) * HWSZ];
        float py = (float)(h - 1 + n / 3) + dy;
        float px = (float)(wx - 1 + n % 3) + dx;
        float y0f = floorf(py), x0f = floorf(px);
        float fy = py - y0f, fx = px - x0f;
        int y0 = (int)y0f, x0 = (int)x0f;
#pragma unroll
        for (int k = 0; k < 4; ++k) {
            int yy = y0 + (k >> 1);
            int xx = x0 + (k & 1);
            bool valid = ((unsigned)yy < HIMG) && ((unsigned)xx < WIMG);
            float wk = ((k >> 1) ? fy : 1.f - fy) * ((k & 1) ? fx : 1.f - fx);
            wk = valid ? wk * mk : 0.f;
            int yc = min(max(yy, 0), HIMG - 1);
            int xc = min(max(xx, 0), WIMG - 1);
            sidx[k][n][pp] = (unsigned short)(yc * WIMG + xc);
            swgt[k][n][pp] = wk;
        }
    }
    __syncthreads();

    int lane = tid & 63, w = tid >> 6;
    int n16 = lane & 15, qd = lane >> 4;
    int pxl = tid >> 3, q8 = tid & 7;      // gather role: pixel 0..31, 16-ch pair 0..7
    int gsub = q8 >> 1;                    // K-sub 0..3
    int goct = (q8 & 1) * 2;               // first of 2 octets within sub
    const unsigned short* yb = y1t + (size_t)b * HWSZ * 128;
    f32x4 acc[2][2];                       // [mi][nt]
#pragma unroll
    for (int mi = 0; mi < 2; ++mi)
#pragma unroll
        for (int nt = 0; nt < 2; ++nt) acc[mi][nt] = (f32x4){0.f, 0.f, 0.f, 0.f};

    for (int n = 0; n < 9; ++n) {
        // gather + bilinear: this thread covers 16 channels (q8*16 ..) of pixel pxl
        float av[2][8];
#pragma unroll
        for (int s = 0; s < 2; ++s)
#pragma unroll
            for (int j = 0; j < 8; ++j) av[s][j] = 0.f;
#pragma unroll
        for (int k = 0; k < 4; ++k) {
            float wk = swgt[k][n][pxl];
            const unsigned short* ys = yb + (size_t)sidx[k][n][pxl] * 128 + q8 * 16;
            short8 v0 = *(const short8*)&ys[0];
            short8 v1 = *(const short8*)&ys[8];
#pragma unroll
            for (int j = 0; j < 8; ++j) {
                av[0][j] = fmaf(wk, b2f((unsigned short)v0[j]), av[0][j]);
                av[1][j] = fmaf(wk, b2f((unsigned short)v1[j]), av[1][j]);
            }
        }
#pragma unroll
        for (int s = 0; s < 2; ++s) {
            short8 v;
#pragma unroll
            for (int j = 0; j < 8; ++j) v[j] = (short)f2b(av[s][j]);
            *(short8*)&sV[BPOS32(gsub, pxl >> 4, pxl & 15, goct + s)] = v;
        }
        __syncthreads();
#pragma unroll
        for (int sub = 0; sub < 4; ++sub) {
            int ks = n * 4 + sub;
            short8 bf[2];
#pragma unroll
            for (int nt = 0; nt < 2; ++nt)
                bf[nt] = *(const short8*)&sV[BPOS32(sub, nt, n16, qd)];
#pragma unroll
            for (int mi = 0; mi < 2; ++mi) {
                short8 af = *(const short8*)&apkd[(size_t)(((2 * w + mi) * 36 + ks) * 64 + lane) * 8];
#pragma unroll
                for (int nt = 0; nt < 2; ++nt)
                    acc[mi][nt] = __builtin_amdgcn_mfma_f32_16x16x32_bf16(af, bf[nt], acc[mi][nt], 0, 0, 0);
            }
        }
        __syncthreads();
    }
    // epilogue: bn2(fused)+silu -> pixel-major bf16, direct 8B stores
    unsigned short* zb = zt + ((size_t)b * HWSZ + p0) * 128;
#pragma unroll
    for (int mi = 0; mi < 2; ++mi)
#pragma unroll
        for (int nt = 0; nt < 2; ++nt) {
            int o0 = (2 * w + mi) * 16 + qd * 4;
            int px = nt * 16 + n16;
            s16x4 v;
#pragma unroll
            for (int r = 0; r < 4; ++r)
                v[r] = (short)f2b(silu_f(acc[mi][nt][r] + bias2[o0 + r]));
            *(s16x4*)&zb[(size_t)px * 128 + o0] = v;
        }
}

// ---------------- cv2: 1x1 (128->256) + bn3 + silu + residual ----------------
// grid 1600, 256 thr. P=32. Transposed MFMA (A = z-pixels, B = weights):
// lane holds 4 consecutive pixels of one o -> float4 residual/store.
__global__ __launch_bounds__(256) void k_cv2(
    const unsigned short* __restrict__ zt, const float* __restrict__ x,
    const unsigned short* __restrict__ apk2, const float* __restrict__ bias3,
    float* __restrict__ out)
{
    int blk = blockIdx.x;
    int b = blk & 7, pt = blk >> 3;        // XCD swizzle, pt 0..199
    int p0 = pt * 32;
    int tid = threadIdx.x;
    int lane = tid & 63, w = tid >> 6;
    int n16 = lane & 15, qd = lane >> 4;
    const unsigned short* zb = zt + ((size_t)b * HWSZ + p0) * 128;
    f32x4 acc[2][4];   // [mt = pixel-tile][ntl = local o-tile]
#pragma unroll
    for (int mt = 0; mt < 2; ++mt)
#pragma unroll
        for (int ntl = 0; ntl < 4; ++ntl) acc[mt][ntl] = (f32x4){0.f, 0.f, 0.f, 0.f};
#pragma unroll
    for (int ks = 0; ks < 4; ++ks) {
        short8 az[2];
#pragma unroll
        for (int mt = 0; mt < 2; ++mt)
            az[mt] = *(const short8*)&zb[(size_t)(mt * 16 + n16) * 128 + ks * 32 + qd * 8];
#pragma unroll
        for (int ntl = 0; ntl < 4; ++ntl) {
            int nt = w * 4 + ntl;
            short8 bw = *(const short8*)&apk2[(size_t)((nt * 4 + ks) * 64 + lane) * 8];
#pragma unroll
            for (int mt = 0; mt < 2; ++mt)
                acc[mt][ntl] = __builtin_amdgcn_mfma_f32_16x16x32_bf16(az[mt], bw, acc[mt][ntl], 0, 0, 0);
        }
    }
    const float* xb = x + (size_t)b * 256 * HWSZ;
    float* ob = out + (size_t)b * 256 * HWSZ;
#pragma unroll
    for (int mt = 0; mt < 2; ++mt) {
        int px = p0 + mt * 16 + qd * 4;
#pragma unroll
        for (int ntl = 0; ntl < 4; ++ntl) {
            int o = (w * 4 + ntl) * 16 + n16;
            float bv = bias3[o];
            size_t base = (size_t)o * HWSZ + px;
            float4 xv = *(const float4*)&xb[base];
            float4 r;
            r.x = xv.x + silu_f(acc[mt][ntl][0] + bv);
            r.y = xv.y + silu_f(acc[mt][ntl][1] + bv);
            r.z = xv.z + silu_f(acc[mt][ntl][2] + bv);
            r.w = xv.w + silu_f(acc[mt][ntl][3] + bv);
            *(float4*)&ob[base] = r;
        }
    }
}

extern "C" void kernel_launch(void* const* d_in, const int* in_sizes, int n_in,
                              void* d_out, int out_size, void* d_ws, size_t ws_size,
                              hipStream_t stream) {
    const float* x     = (const float*)d_in[0];
    const float* cv1w  = (const float*)d_in[1];
    const float* bn1g  = (const float*)d_in[2];
    const float* bn1b  = (const float*)d_in[3];
    const float* bn1m  = (const float*)d_in[4];
    const float* bn1v  = (const float*)d_in[5];
    const float* offw  = (const float*)d_in[6];
    const float* offb  = (const float*)d_in[7];
    const float* dcnw  = (const float*)d_in[8];
    const float* dcnb  = (const float*)d_in[9];
    const float* bn2g  = (const float*)d_in[10];
    const float* bn2b  = (const float*)d_in[11];
    const float* bn2m  = (const float*)d_in[12];
    const float* bn2v  = (const float*)d_in[13];
    const float* cv2w  = (const float*)d_in[14];
    const float* bn3g  = (const float*)d_in[15];
    const float* bn3b  = (const float*)d_in[16];
    const float* bn3m  = (const float*)d_in[17];
    const float* bn3v  = (const float*)d_in[18];
    float* out = (float*)d_out;

    // workspace layout (float units)
    float* base = (float*)d_ws;
    unsigned short* y1t = (unsigned short*)base;                 // 8*6400*128 bf16 = 3,276,800 f
    float* raw   = base + 3276800;                               // 8*27*6400   = 1,382,400 f
    unsigned short* zt  = (unsigned short*)(base + 4659200);     // 8*6400*128 bf16 = 3,276,800 f
    unsigned short* apk1 = (unsigned short*)(base + 7936000);    // 32768  ush = 16384 f
    unsigned short* apko = (unsigned short*)(base + 7952384);    // 36864  ush = 18432 f
    unsigned short* apkd = (unsigned short*)(base + 7970816);    // 147456 ush = 73728 f
    unsigned short* apk2 = (unsigned short*)(base + 8044544);    // 32768  ush = 16384 f
    float* bias1 = base + 8060928;                               // 128
    float* biaso = base + 8061056;                               // 27 (pad 32)
    float* bias2 = base + 8061088;                               // 128
    float* bias3 = base + 8061216;                               // 256

    k_prep<<<979, 256, 0, stream>>>(cv1w, bn1g, bn1b, bn1m, bn1v,
                                    offw, offb, dcnw, dcnb,
                                    bn2g, bn2b, bn2m, bn2v,
                                    cv2w, bn3g, bn3b, bn3m, bn3v,
                                    apk1, apko, apkd, apk2,
                                    bias1, biaso, bias2, bias3);
    k_cv1<<<800, 256, 0, stream>>>(x, apk1, bias1, y1t);
    k_off<<<800, 256, 0, stream>>>(y1t, apko, biaso, raw);
    k_dcn<<<1600, 256, 0, stream>>>(y1t, raw, apkd, bias2, zt);
    k_cv2<<<1600, 256, 0, stream>>>(zt, x, apk2, bias3, out);
}